// Round 3
// baseline (876.736 us; speedup 1.0000x reference)
//
#include <hip/hip_runtime.h>

#define N_NODES 50000
#define N_EDGES 800000
#define IN_DIM  768
#define HID_DIM 512
#define OUT_DIM 256
#define M_PAD   50048   // 391 * 128

typedef __attribute__((ext_vector_type(8))) short shortx8;        // 8 bf16 = 16 B
typedef __attribute__((ext_vector_type(4))) short shortx4;        // 4 bf16 = 8 B
typedef __attribute__((ext_vector_type(4))) float floatx4;        // MFMA C/D + NT stores

#define AS1 __attribute__((address_space(1)))
#define AS3 __attribute__((address_space(3)))

__device__ __forceinline__ unsigned short f2bf_rne(float f) {
    unsigned int u = __float_as_uint(f);
    unsigned int r = u + 0x7FFFu + ((u >> 16) & 1u);
    return (unsigned short)(r >> 16);
}
__device__ __forceinline__ float bf2f(unsigned short h) {
    return __uint_as_float(((unsigned int)h) << 16);
}

// ---------------------------------------------------------------------------
// Graph prep
// ---------------------------------------------------------------------------
__global__ void count_deg_kernel(const int* __restrict__ dst, int* __restrict__ deg,
                                 int n_edges) {
    int e = blockIdx.x * blockDim.x + threadIdx.x;
    if (e < n_edges) atomicAdd(&deg[dst[e]], 1);
}

#define SCAN_B 256
#define N_SCAN_BLOCKS ((N_NODES + SCAN_B - 1) / SCAN_B)   // 196

__global__ void block_sum_kernel(const int* __restrict__ deg, int* __restrict__ partials,
                                 int n) {
    __shared__ int sm[SCAN_B];
    int i = blockIdx.x * SCAN_B + threadIdx.x;
    sm[threadIdx.x] = (i < n) ? deg[i] : 0;
    __syncthreads();
    for (int off = SCAN_B / 2; off > 0; off >>= 1) {
        if (threadIdx.x < off) sm[threadIdx.x] += sm[threadIdx.x + off];
        __syncthreads();
    }
    if (threadIdx.x == 0) partials[blockIdx.x] = sm[0];
}

__global__ void scan_partials_kernel(const int* __restrict__ partials,
                                     int* __restrict__ bases, int nb) {
    __shared__ int sm[SCAN_B];
    int v = (threadIdx.x < nb) ? partials[threadIdx.x] : 0;
    sm[threadIdx.x] = v;
    __syncthreads();
    for (int off = 1; off < SCAN_B; off <<= 1) {
        int t = (threadIdx.x >= off) ? sm[threadIdx.x - off] : 0;
        __syncthreads();
        sm[threadIdx.x] += t;
        __syncthreads();
    }
    if (threadIdx.x < nb) bases[threadIdx.x] = sm[threadIdx.x] - v;   // exclusive
}

__global__ void finalize_scan_kernel(const int* __restrict__ deg, const int* __restrict__ bases,
                                     int* __restrict__ offsets, int* __restrict__ cursor,
                                     float* __restrict__ dinv, int n) {
    __shared__ int sm[SCAN_B];
    int i = blockIdx.x * SCAN_B + threadIdx.x;
    int v = (i < n) ? deg[i] : 0;
    sm[threadIdx.x] = v;
    __syncthreads();
    for (int off = 1; off < SCAN_B; off <<= 1) {
        int t = (threadIdx.x >= off) ? sm[threadIdx.x - off] : 0;
        __syncthreads();
        sm[threadIdx.x] += t;
        __syncthreads();
    }
    if (i < n) {
        int incl = bases[blockIdx.x] + sm[threadIdx.x];
        int o = incl - v;
        offsets[i] = o;
        cursor[i]  = o;
        dinv[i]    = rsqrtf((float)(v + 1));
        if (i == n - 1) offsets[n] = incl;
    }
}

__global__ void fill_csr_kernel(const int* __restrict__ src, const int* __restrict__ dst,
                                int* __restrict__ cursor, int* __restrict__ csr_src,
                                int n_edges) {
    int e = blockIdx.x * blockDim.x + threadIdx.x;
    if (e < n_edges) {
        int p = atomicAdd(&cursor[dst[e]], 1);
        csr_src[p] = src[e];
    }
}

// ---------------------------------------------------------------------------
// fp32 -> bf16 hi/lo split
// ---------------------------------------------------------------------------
__global__ void convert_split_kernel(const float* __restrict__ x,
                                     unsigned short* __restrict__ xhi,
                                     unsigned short* __restrict__ xlo,
                                     long long n4) {
    long long i = (long long)blockIdx.x * blockDim.x + threadIdx.x;
    if (i >= n4) return;
    float4 v = *reinterpret_cast<const float4*>(x + i * 4);
    ushort4 h, l;
    h.x = f2bf_rne(v.x); l.x = f2bf_rne(v.x - bf2f(h.x));
    h.y = f2bf_rne(v.y); l.y = f2bf_rne(v.y - bf2f(h.y));
    h.z = f2bf_rne(v.z); l.z = f2bf_rne(v.z - bf2f(h.z));
    h.w = f2bf_rne(v.w); l.w = f2bf_rne(v.w - bf2f(h.w));
    *reinterpret_cast<ushort4*>(xhi + i * 4) = h;
    *reinterpret_cast<ushort4*>(xlo + i * 4) = l;
}

// ---------------------------------------------------------------------------
// W [K][N] fp32 -> Wt [N][K] bf16 hi/lo
// ---------------------------------------------------------------------------
__global__ void transpose_split_kernel(const float* __restrict__ W,
                                       unsigned short* __restrict__ Whi,
                                       unsigned short* __restrict__ Wlo,
                                       int K, int N) {
    __shared__ float tile[32][33];
    int n0 = blockIdx.x * 32, k0 = blockIdx.y * 32;
    int tx = threadIdx.x, ty = threadIdx.y;
    tile[ty][tx] = W[(size_t)(k0 + ty) * N + n0 + tx];
    __syncthreads();
    float v = tile[tx][ty];
    unsigned short h = f2bf_rne(v);
    size_t o = (size_t)(n0 + ty) * K + k0 + tx;
    Whi[o] = h;
    Wlo[o] = f2bf_rne(v - bf2f(h));
}

// ---------------------------------------------------------------------------
// bf16x3 split MFMA GEMM; output plain bf16 (feeds the gather):
//   C[r][c] = bf16( (sum_k A[r][k]*B[c][k]) * dinv[r] )
//
// Round-3 structure:
//  - T1 XCD-aware bijective block swizzle (verified: FETCH 340->99 MB).
//  - T2 both-sides XOR swizzle on A (verified: SQ_LDS_BANK_CONFLICT -> 0).
//  - B-fragments load DIRECT global->VGPR (no LDS): B panel is ~1.5 MB,
//    L2-resident, fragment-shaped in Wt[N][K]. Halves LDS-pipe traffic
//    (16 -> 8 ds_read_b128 per wave per step) and halves staging volume.
//  - A double-buffered at the SAME 32 KiB footprint (As[2][2][128][32]);
//    stage(k+1) issued at top of step k, ONE __syncthreads per step
//    (T3-minimum template) -> stage latency overlaps MFMA + ds_read.
//  - launch_bounds(256,3): ~148 total regs -> 12 waves/CU (3 blocks).
// ---------------------------------------------------------------------------
#define GBK 32

__global__ __launch_bounds__(256, 3)
void gemm_bf16x3_kernel(const unsigned short* __restrict__ Ahi,
                        const unsigned short* __restrict__ Alo,
                        const unsigned short* __restrict__ Bhi,
                        const unsigned short* __restrict__ Blo,
                        const float* __restrict__ dinv,
                        unsigned short* __restrict__ C,
                        int M, int N, int K) {
    // [buf][hi/lo][row][k] : 2*2*128*32*2B = 32 KiB total
    __shared__ __align__(16) unsigned short As[2][2][128][GBK];

    const int tid  = threadIdx.x;
    const int lane = tid & 63;
    const int wave = tid >> 6;

    // --- XCD-aware bijective swizzle (m204 formula) ---
    const int gx   = gridDim.x;
    const int nwg  = gx * gridDim.y;
    const int blin = blockIdx.y * gx + blockIdx.x;      // hw linear id, x fastest
    const int qq   = nwg >> 3, rr = nwg & 7;
    const int xcd  = blin & 7, idx = blin >> 3;
    const int tt   = (xcd < rr ? xcd * (qq + 1) : rr * (qq + 1) + (xcd - rr) * qq) + idx;
    const int rowBase = (tt / gx) * 128;
    const int colBase = (tt % gx) * 128;

    // --- A staging map: wave w stages {hi,lo}[rows rq..rq+63], 4 issues each ---
    const int hl = wave >> 1;                 // 0: hi, 1: lo
    const int rq = (wave & 1) * 64;
    const unsigned short* gsrc = hl ? Alo : Ahi;
    unsigned short* lbase = &As[0][hl][rq][0];
    // pre-swizzled global col-group so LDS[r][s] holds col-group s ^ ((r>>1)&3)
    const int cg = ((lane & 3) ^ ((lane >> 3) & 3)) * 8;
    const size_t laneRowOff = (size_t)(rowBase + rq + (lane >> 2)) * K + cg;

    const int m0  = (wave & 1) * 64;          // output row half
    const int n0  = (wave >> 1) * 64;         // output col half
    const int r16 = lane & 15;
    const int kq  = (lane >> 4) * 8;          // B-fragment k sub-offset
    // matching read-side XOR for A: logical col-group (lane>>4), slot XORed
    const int kswz = ((lane >> 4) ^ ((r16 >> 1) & 3)) * 8;

    // --- B fragment base pointers (global, L2-resident; no LDS for B) ---
    const unsigned short* bph[4];
    const unsigned short* bpl[4];
#pragma unroll
    for (int j = 0; j < 4; j++) {
        int col = colBase + n0 + j * 16 + r16;
        bph[j] = Bhi + (size_t)col * K + kq;
        bpl[j] = Blo + (size_t)col * K + kq;
    }

    floatx4 acc[4][4] = {};

    // prologue: stage K-tile 0 into buffer 0
#pragma unroll
    for (int j = 0; j < 4; j++) {
        const unsigned short* g = gsrc + laneRowOff + (size_t)(j * 16) * K;
        __builtin_amdgcn_global_load_lds((const AS1 void*)g,
                                         (AS3 void*)(lbase + j * 16 * GBK), 16, 0, 0);
    }
    __syncthreads();

    int cur = 0;
    for (int k0 = 0; k0 < K; k0 += GBK) {
        // stage next K-tile into other buffer FIRST (in flight across MFMA;
        // readers of that buffer finished before the previous barrier)
        if (k0 + GBK < K) {
            unsigned short* dstb = lbase + (cur ^ 1) * (2 * 128 * GBK);
#pragma unroll
            for (int j = 0; j < 4; j++) {
                const unsigned short* g =
                    gsrc + laneRowOff + (size_t)(j * 16) * K + (k0 + GBK);
                __builtin_amdgcn_global_load_lds((const AS1 void*)g,
                                                 (AS3 void*)(dstb + j * 16 * GBK),
                                                 16, 0, 0);
            }
        }

        // B fragments direct from global (L2 hit), issued early
        shortx8 bh[4], bv[4];
#pragma unroll
        for (int j = 0; j < 4; j++) {
            bh[j] = *reinterpret_cast<const shortx8*>(bph[j] + k0);
            bv[j] = *reinterpret_cast<const shortx8*>(bpl[j] + k0);
        }
        // A fragments from LDS (swizzled, conflict-free)
        shortx8 ah[4], al[4];
#pragma unroll
        for (int i = 0; i < 4; i++) {
            ah[i] = *reinterpret_cast<const shortx8*>(&As[cur][0][m0 + i * 16 + r16][kswz]);
            al[i] = *reinterpret_cast<const shortx8*>(&As[cur][1][m0 + i * 16 + r16][kswz]);
        }
#pragma unroll
        for (int i = 0; i < 4; i++)
#pragma unroll
            for (int j = 0; j < 4; j++) {
                acc[i][j] = __builtin_amdgcn_mfma_f32_16x16x32_bf16(ah[i], bh[j], acc[i][j], 0, 0, 0);
                acc[i][j] = __builtin_amdgcn_mfma_f32_16x16x32_bf16(ah[i], bv[j], acc[i][j], 0, 0, 0);
                acc[i][j] = __builtin_amdgcn_mfma_f32_16x16x32_bf16(al[i], bh[j], acc[i][j], 0, 0, 0);
            }
        __syncthreads();   // drains vmcnt(0): next tile staged; lgkm: reads done
        cur ^= 1;
    }

#pragma unroll
    for (int i = 0; i < 4; i++) {
        int rsub = rowBase + m0 + i * 16 + (lane >> 4) * 4;
#pragma unroll
        for (int j = 0; j < 4; j++) {
            int col = colBase + n0 + j * 16 + r16;
#pragma unroll
            for (int r = 0; r < 4; r++) {
                int row = rsub + r;
                if (row < M) C[(size_t)row * N + col] = f2bf_rne(acc[i][j][r] * dinv[row]);
            }
        }
    }
}

// ---------------------------------------------------------------------------
// Aggregation, layer 1 (F=512 bf16, 64 thr, thread owns 8 channels = 16 B/row):
// out = relu((hs[self] + sum hs[nbr]) * dinv + b), written bf16 hi/lo (NT).
// ---------------------------------------------------------------------------
__global__ __launch_bounds__(64)
void aggregate1_kernel(const unsigned short* __restrict__ hs, const int* __restrict__ offsets,
                       const int* __restrict__ csr_src, const float* __restrict__ dinv,
                       const float* __restrict__ bias,
                       unsigned short* __restrict__ yhi,
                       unsigned short* __restrict__ ylo) {
    __shared__ int idxs[64];
    const int node = blockIdx.x;
    const int c = threadIdx.x * 8;
    const unsigned short* hp = hs + c;

    float acc[8];
    {
        shortx8 r = *reinterpret_cast<const shortx8*>(hp + (size_t)node * HID_DIM);
#pragma unroll
        for (int q = 0; q < 8; q++) acc[q] = bf2f((unsigned short)r[q]);
    }
    int beg = offsets[node], end = offsets[node + 1];
    for (int base = beg; base < end; base += 64) {
        int cnt = min(64, end - base);
        __syncthreads();
        if ((int)threadIdx.x < cnt) idxs[threadIdx.x] = csr_src[base + threadIdx.x];
        __syncthreads();
        int j = 0;
        for (; j + 8 <= cnt; j += 8) {
            shortx8 r0 = *reinterpret_cast<const shortx8*>(hp + (size_t)idxs[j + 0] * HID_DIM);
            shortx8 r1 = *reinterpret_cast<const shortx8*>(hp + (size_t)idxs[j + 1] * HID_DIM);
            shortx8 r2 = *reinterpret_cast<const shortx8*>(hp + (size_t)idxs[j + 2] * HID_DIM);
            shortx8 r3 = *reinterpret_cast<const shortx8*>(hp + (size_t)idxs[j + 3] * HID_DIM);
            shortx8 r4 = *reinterpret_cast<const shortx8*>(hp + (size_t)idxs[j + 4] * HID_DIM);
            shortx8 r5 = *reinterpret_cast<const shortx8*>(hp + (size_t)idxs[j + 5] * HID_DIM);
            shortx8 r6 = *reinterpret_cast<const shortx8*>(hp + (size_t)idxs[j + 6] * HID_DIM);
            shortx8 r7 = *reinterpret_cast<const shortx8*>(hp + (size_t)idxs[j + 7] * HID_DIM);
#pragma unroll
            for (int q = 0; q < 8; q++)
                acc[q] += ((bf2f((unsigned short)r0[q]) + bf2f((unsigned short)r1[q]))
                         + (bf2f((unsigned short)r2[q]) + bf2f((unsigned short)r3[q])))
                        + ((bf2f((unsigned short)r4[q]) + bf2f((unsigned short)r5[q]))
                         + (bf2f((unsigned short)r6[q]) + bf2f((unsigned short)r7[q])));
        }
        for (; j < cnt; j++) {
            shortx8 r = *reinterpret_cast<const shortx8*>(hp + (size_t)idxs[j] * HID_DIM);
#pragma unroll
            for (int q = 0; q < 8; q++) acc[q] += bf2f((unsigned short)r[q]);
        }
    }
    float dv = dinv[node];
    floatx4 b0 = *reinterpret_cast<const floatx4*>(bias + c);
    floatx4 b1 = *reinterpret_cast<const floatx4*>(bias + c + 4);
    shortx8 h8, l8;
#pragma unroll
    for (int q = 0; q < 8; q++) {
        float bq = (q < 4) ? b0[q] : b1[q - 4];
        float o = fmaxf(acc[q] * dv + bq, 0.f);
        unsigned short h = f2bf_rne(o);
        h8[q] = (short)h;
        l8[q] = (short)f2bf_rne(o - bf2f(h));
    }
    __builtin_nontemporal_store(h8, reinterpret_cast<shortx8*>(yhi + (size_t)node * HID_DIM + c));
    __builtin_nontemporal_store(l8, reinterpret_cast<shortx8*>(ylo + (size_t)node * HID_DIM + c));
}

// ---------------------------------------------------------------------------
// Aggregation, layer 2 (F=256 bf16, 64 thr, thread owns 4 channels = 8 B/row):
// fp32 out, no activation, NT store.
// ---------------------------------------------------------------------------
__global__ __launch_bounds__(64)
void aggregate2_kernel(const unsigned short* __restrict__ hs, const int* __restrict__ offsets,
                       const int* __restrict__ csr_src, const float* __restrict__ dinv,
                       const float* __restrict__ bias, float* __restrict__ out) {
    __shared__ int idxs[64];
    const int node = blockIdx.x;
    const int c = threadIdx.x * 4;
    const unsigned short* hp = hs + c;

    float acc[4];
    {
        shortx4 r = *reinterpret_cast<const shortx4*>(hp + (size_t)node * OUT_DIM);
#pragma unroll
        for (int q = 0; q < 4; q++) acc[q] = bf2f((unsigned short)r[q]);
    }
    int beg = offsets[node], end = offsets[node + 1];
    for (int base = beg; base < end; base += 64) {
        int cnt = min(64, end - base);
        __syncthreads();
        if ((int)threadIdx.x < cnt) idxs[threadIdx.x] = csr_src[base + threadIdx.x];
        __syncthreads();
        int j = 0;
        for (; j + 8 <= cnt; j += 8) {
            shortx4 r0 = *reinterpret_cast<const shortx4*>(hp + (size_t)idxs[j + 0] * OUT_DIM);
            shortx4 r1 = *reinterpret_cast<const shortx4*>(hp + (size_t)idxs[j + 1] * OUT_DIM);
            shortx4 r2 = *reinterpret_cast<const shortx4*>(hp + (size_t)idxs[j + 2] * OUT_DIM);
            shortx4 r3 = *reinterpret_cast<const shortx4*>(hp + (size_t)idxs[j + 3] * OUT_DIM);
            shortx4 r4 = *reinterpret_cast<const shortx4*>(hp + (size_t)idxs[j + 4] * OUT_DIM);
            shortx4 r5 = *reinterpret_cast<const shortx4*>(hp + (size_t)idxs[j + 5] * OUT_DIM);
            shortx4 r6 = *reinterpret_cast<const shortx4*>(hp + (size_t)idxs[j + 6] * OUT_DIM);
            shortx4 r7 = *reinterpret_cast<const shortx4*>(hp + (size_t)idxs[j + 7] * OUT_DIM);
#pragma unroll
            for (int q = 0; q < 4; q++)
                acc[q] += ((bf2f((unsigned short)r0[q]) + bf2f((unsigned short)r1[q]))
                         + (bf2f((unsigned short)r2[q]) + bf2f((unsigned short)r3[q])))
                        + ((bf2f((unsigned short)r4[q]) + bf2f((unsigned short)r5[q]))
                         + (bf2f((unsigned short)r6[q]) + bf2f((unsigned short)r7[q])));
        }
        for (; j < cnt; j++) {
            shortx4 r = *reinterpret_cast<const shortx4*>(hp + (size_t)idxs[j] * OUT_DIM);
#pragma unroll
            for (int q = 0; q < 4; q++) acc[q] += bf2f((unsigned short)r[q]);
        }
    }
    float dv = dinv[node];
    floatx4 b = *reinterpret_cast<const floatx4*>(bias + c);
    floatx4 o = { acc[0] * dv + b[0], acc[1] * dv + b[1],
                  acc[2] * dv + b[2], acc[3] * dv + b[3] };
    __builtin_nontemporal_store(o, reinterpret_cast<floatx4*>(out + (size_t)node * OUT_DIM + c));
}

// ---------------------------------------------------------------------------
extern "C" void kernel_launch(void* const* d_in, const int* in_sizes, int n_in,
                              void* d_out, int out_size, void* d_ws, size_t ws_size,
                              hipStream_t stream) {
    const float* x    = (const float*)d_in[0];
    const int*   edge = (const int*)d_in[1];
    const float* W1   = (const float*)d_in[2];
    const float* b1   = (const float*)d_in[3];
    const float* W2   = (const float*)d_in[4];
    const float* b2   = (const float*)d_in[5];
    float* out = (float*)d_out;

    const int* src = edge;
    const int* dst = edge + N_EDGES;

    char*  ws  = (char*)d_ws;
    size_t off = 0;
    auto alloc = [&](size_t bytes) -> void* {
        void* p = ws + off;
        off += (bytes + 255) & ~(size_t)255;
        return p;
    };
    int*   deg      = (int*)alloc((size_t)N_NODES * 4);
    float* dinv     = (float*)alloc((size_t)N_NODES * 4);
    int*   offsets  = (int*)alloc((size_t)(N_NODES + 1) * 4);
    int*   cursor   = (int*)alloc((size_t)N_NODES * 4);
    int*   csr_src  = (int*)alloc((size_t)N_EDGES * 4);
    int*   partials = (int*)alloc((size_t)N_SCAN_BLOCKS * 4);
    int*   bases    = (int*)alloc((size_t)N_SCAN_BLOCKS * 4);
    unsigned short* xhi   = (unsigned short*)alloc((size_t)M_PAD * IN_DIM * 2);
    unsigned short* xlo   = (unsigned short*)alloc((size_t)M_PAD * IN_DIM * 2);
    unsigned short* w1thi = (unsigned short*)alloc((size_t)HID_DIM * IN_DIM * 2);
    unsigned short* w1tlo = (unsigned short*)alloc((size_t)HID_DIM * IN_DIM * 2);
    unsigned short* w2thi = (unsigned short*)alloc((size_t)OUT_DIM * HID_DIM * 2);
    unsigned short* w2tlo = (unsigned short*)alloc((size_t)OUT_DIM * HID_DIM * 2);
    unsigned short* hs = (unsigned short*)alloc((size_t)N_NODES * HID_DIM * 2);  // bf16 pre-agg, reused L2

    unsigned short* y1hi = xhi;   // alias dead x regions
    unsigned short* y1lo = xlo;

    // ---- graph prep ----
    hipMemsetAsync(deg, 0, (size_t)N_NODES * 4, stream);
    count_deg_kernel<<<(N_EDGES + 255) / 256, 256, 0, stream>>>(dst, deg, N_EDGES);
    block_sum_kernel<<<N_SCAN_BLOCKS, SCAN_B, 0, stream>>>(deg, partials, N_NODES);
    scan_partials_kernel<<<1, SCAN_B, 0, stream>>>(partials, bases, N_SCAN_BLOCKS);
    finalize_scan_kernel<<<N_SCAN_BLOCKS, SCAN_B, 0, stream>>>(deg, bases, offsets, cursor,
                                                               dinv, N_NODES);
    fill_csr_kernel<<<(N_EDGES + 255) / 256, 256, 0, stream>>>(src, dst, cursor, csr_src, N_EDGES);

    // ---- precision split ----
    long long n4x = (long long)N_NODES * IN_DIM / 4;
    convert_split_kernel<<<(int)((n4x + 255) / 256), 256, 0, stream>>>(x, xhi, xlo, n4x);
    transpose_split_kernel<<<dim3(HID_DIM / 32, IN_DIM / 32), dim3(32, 32), 0, stream>>>(
        W1, w1thi, w1tlo, IN_DIM, HID_DIM);
    transpose_split_kernel<<<dim3(OUT_DIM / 32, HID_DIM / 32), dim3(32, 32), 0, stream>>>(
        W2, w2thi, w2tlo, HID_DIM, OUT_DIM);

    // ---- layer 1 ----
    gemm_bf16x3_kernel<<<dim3(HID_DIM / 128, M_PAD / 128), 256, 0, stream>>>(
        xhi, xlo, w1thi, w1tlo, dinv, hs, N_NODES, HID_DIM, IN_DIM);
    aggregate1_kernel<<<N_NODES, 64, 0, stream>>>(
        hs, offsets, csr_src, dinv, b1, y1hi, y1lo);

    // ---- layer 2 ----
    gemm_bf16x3_kernel<<<dim3(OUT_DIM / 128, M_PAD / 128), 256, 0, stream>>>(
        y1hi, y1lo, w2thi, w2tlo, dinv, hs, N_NODES, OUT_DIM, HID_DIM);
    aggregate2_kernel<<<N_NODES, 64, 0, stream>>>(
        hs, offsets, csr_src, dinv, b2, out);
}

// Round 4
// 792.608 us; speedup vs baseline: 1.1061x; 1.1061x over previous
//
#include <hip/hip_runtime.h>

#define N_NODES 50000
#define N_EDGES 800000
#define IN_DIM  768
#define HID_DIM 512
#define OUT_DIM 256
#define M_PAD   50048   // 391 * 128

typedef __attribute__((ext_vector_type(8))) short shortx8;        // 8 bf16 = 16 B
typedef __attribute__((ext_vector_type(4))) short shortx4;        // 4 bf16 = 8 B
typedef __attribute__((ext_vector_type(4))) float floatx4;        // MFMA C/D + NT stores

#define AS1 __attribute__((address_space(1)))
#define AS3 __attribute__((address_space(3)))

__device__ __forceinline__ unsigned short f2bf_rne(float f) {
    unsigned int u = __float_as_uint(f);
    unsigned int r = u + 0x7FFFu + ((u >> 16) & 1u);
    return (unsigned short)(r >> 16);
}
__device__ __forceinline__ float bf2f(unsigned short h) {
    return __uint_as_float(((unsigned int)h) << 16);
}

// ---------------------------------------------------------------------------
// Graph prep
// ---------------------------------------------------------------------------
__global__ void count_deg_kernel(const int* __restrict__ dst, int* __restrict__ deg,
                                 int n_edges) {
    int e = blockIdx.x * blockDim.x + threadIdx.x;
    if (e < n_edges) atomicAdd(&deg[dst[e]], 1);
}

#define SCAN_B 256
#define N_SCAN_BLOCKS ((N_NODES + SCAN_B - 1) / SCAN_B)   // 196

__global__ void block_sum_kernel(const int* __restrict__ deg, int* __restrict__ partials,
                                 int n) {
    __shared__ int sm[SCAN_B];
    int i = blockIdx.x * SCAN_B + threadIdx.x;
    sm[threadIdx.x] = (i < n) ? deg[i] : 0;
    __syncthreads();
    for (int off = SCAN_B / 2; off > 0; off >>= 1) {
        if (threadIdx.x < off) sm[threadIdx.x] += sm[threadIdx.x + off];
        __syncthreads();
    }
    if (threadIdx.x == 0) partials[blockIdx.x] = sm[0];
}

__global__ void scan_partials_kernel(const int* __restrict__ partials,
                                     int* __restrict__ bases, int nb) {
    __shared__ int sm[SCAN_B];
    int v = (threadIdx.x < nb) ? partials[threadIdx.x] : 0;
    sm[threadIdx.x] = v;
    __syncthreads();
    for (int off = 1; off < SCAN_B; off <<= 1) {
        int t = (threadIdx.x >= off) ? sm[threadIdx.x - off] : 0;
        __syncthreads();
        sm[threadIdx.x] += t;
        __syncthreads();
    }
    if (threadIdx.x < nb) bases[threadIdx.x] = sm[threadIdx.x] - v;   // exclusive
}

__global__ void finalize_scan_kernel(const int* __restrict__ deg, const int* __restrict__ bases,
                                     int* __restrict__ offsets, int* __restrict__ cursor,
                                     float* __restrict__ dinv, int n) {
    __shared__ int sm[SCAN_B];
    int i = blockIdx.x * SCAN_B + threadIdx.x;
    int v = (i < n) ? deg[i] : 0;
    sm[threadIdx.x] = v;
    __syncthreads();
    for (int off = 1; off < SCAN_B; off <<= 1) {
        int t = (threadIdx.x >= off) ? sm[threadIdx.x - off] : 0;
        __syncthreads();
        sm[threadIdx.x] += t;
        __syncthreads();
    }
    if (i < n) {
        int incl = bases[blockIdx.x] + sm[threadIdx.x];
        int o = incl - v;
        offsets[i] = o;
        cursor[i]  = o;
        dinv[i]    = rsqrtf((float)(v + 1));
        if (i == n - 1) offsets[n] = incl;
    }
}

__global__ void fill_csr_kernel(const int* __restrict__ src, const int* __restrict__ dst,
                                int* __restrict__ cursor, int* __restrict__ csr_src,
                                int n_edges) {
    int e = blockIdx.x * blockDim.x + threadIdx.x;
    if (e < n_edges) {
        int p = atomicAdd(&cursor[dst[e]], 1);
        csr_src[p] = src[e];
    }
}

// ---------------------------------------------------------------------------
// fp32 -> bf16 hi/lo split
// ---------------------------------------------------------------------------
__global__ void convert_split_kernel(const float* __restrict__ x,
                                     unsigned short* __restrict__ xhi,
                                     unsigned short* __restrict__ xlo,
                                     long long n4) {
    long long i = (long long)blockIdx.x * blockDim.x + threadIdx.x;
    if (i >= n4) return;
    float4 v = *reinterpret_cast<const float4*>(x + i * 4);
    ushort4 h, l;
    h.x = f2bf_rne(v.x); l.x = f2bf_rne(v.x - bf2f(h.x));
    h.y = f2bf_rne(v.y); l.y = f2bf_rne(v.y - bf2f(h.y));
    h.z = f2bf_rne(v.z); l.z = f2bf_rne(v.z - bf2f(h.z));
    h.w = f2bf_rne(v.w); l.w = f2bf_rne(v.w - bf2f(h.w));
    *reinterpret_cast<ushort4*>(xhi + i * 4) = h;
    *reinterpret_cast<ushort4*>(xlo + i * 4) = l;
}

// ---------------------------------------------------------------------------
// W [K][N] fp32 -> Wt [N][K] bf16 hi/lo
// ---------------------------------------------------------------------------
__global__ void transpose_split_kernel(const float* __restrict__ W,
                                       unsigned short* __restrict__ Whi,
                                       unsigned short* __restrict__ Wlo,
                                       int K, int N) {
    __shared__ float tile[32][33];
    int n0 = blockIdx.x * 32, k0 = blockIdx.y * 32;
    int tx = threadIdx.x, ty = threadIdx.y;
    tile[ty][tx] = W[(size_t)(k0 + ty) * N + n0 + tx];
    __syncthreads();
    float v = tile[tx][ty];
    unsigned short h = f2bf_rne(v);
    size_t o = (size_t)(n0 + ty) * K + k0 + tx;
    Whi[o] = h;
    Wlo[o] = f2bf_rne(v - bf2f(h));
}

// ---------------------------------------------------------------------------
// bf16x3 split MFMA GEMM; output plain bf16 (feeds the gather):
//   C[r][c] = bf16( (sum_k A[r][k]*B[c][k]) * dinv[r] )
//
// Round-4 structure:
//  - T1 XCD swizzle (verified: FETCH 340->~99 MB) + T2 XOR swizzle
//    (verified: SQ_LDS_BANK_CONFLICT -> 0). B back in LDS (round-3's
//    direct-B coupled B waits to the A-prefetch via the shared vmcnt
//    FIFO -> serialized; reverted).
//  - T3+T4: double-buffered A AND B (64 KiB), counted-vmcnt pipeline with
//    RAW s_barrier (fused asm blocks). Staging for tile t+2 is issued
//    before the MFMA cluster and stays IN FLIGHT across the trailing
//    barrier (vmcnt(8), never 0, in the main loop). This is the m218
//    pattern; __syncthreads would drain vmcnt(0) and kill it (r1 result).
//  - T5 setprio(1) around the MFMA cluster (phase-split schedule -> waves
//    have role diversity -> arbitration pays, per m218b).
// vmcnt ledger (per wave, 8 gload_lds per tile): prologue stages t0,t1
// (16 out) -> vmcnt(8) = t0 done. Iter t: stage t+2 (16 out) -> MFMA ->
// vmcnt(8) = t+1 done, t+2 in flight. Tail (t+2>=nt): vmcnt(0).
// ---------------------------------------------------------------------------
#define GBK 32

__global__ __launch_bounds__(256, 2)
void gemm_bf16x3_kernel(const unsigned short* __restrict__ Ahi,
                        const unsigned short* __restrict__ Alo,
                        const unsigned short* __restrict__ Bhi,
                        const unsigned short* __restrict__ Blo,
                        const float* __restrict__ dinv,
                        unsigned short* __restrict__ C,
                        int M, int N, int K) {
    // [buf][hi/lo][row][k] : 2*2*128*32*2B = 32 KiB each -> 64 KiB total
    __shared__ __align__(16) unsigned short As[2][2][128][GBK];
    __shared__ __align__(16) unsigned short Bs[2][2][128][GBK];

    const int tid  = threadIdx.x;
    const int lane = tid & 63;
    const int wave = tid >> 6;

    // --- XCD-aware bijective swizzle (m204 formula) ---
    const int gx   = gridDim.x;
    const int nwg  = gx * gridDim.y;
    const int blin = blockIdx.y * gx + blockIdx.x;      // hw linear id, x fastest
    const int qq   = nwg >> 3, rr = nwg & 7;
    const int xcd  = blin & 7, idx = blin >> 3;
    const int tt   = (xcd < rr ? xcd * (qq + 1) : rr * (qq + 1) + (xcd - rr) * qq) + idx;
    const int rowBase = (tt / gx) * 128;
    const int colBase = (tt % gx) * 128;

    // staging: wave0->A-hi, wave1->A-lo, wave2->B-hi, wave3->B-lo
    const unsigned short* gsrc =
        (wave == 0) ? Ahi : (wave == 1) ? Alo : (wave == 2) ? Bhi : Blo;
    unsigned short* lplane =
        (wave == 0) ? &As[0][0][0][0] : (wave == 1) ? &As[0][1][0][0]
      : (wave == 2) ? &Bs[0][0][0][0] : &Bs[0][1][0][0];
    const size_t bufStride = (size_t)2 * 128 * GBK;     // As[0]->As[1] distance
    const int rbase = (wave < 2) ? rowBase : colBase;
    // pre-swizzled global col-group so LDS[r][s] holds col-group s ^ ((r>>1)&3)
    const int cg = ((lane & 3) ^ ((lane >> 3) & 3)) * 8;
    const size_t laneRowOff = (size_t)(rbase + (lane >> 2)) * K + cg;

    const int m0  = (wave & 1) * 64;
    const int n0  = (wave >> 1) * 64;
    const int r16 = lane & 15;
    // matching read-side XOR: logical col-group (lane>>4), physical slot XORed
    const int kswz = ((lane >> 4) ^ ((r16 >> 1) & 3)) * 8;

    floatx4 acc[4][4] = {};
    const int nt = K / GBK;

    auto STAGE = [&](int t, int buf) {
        unsigned short* d = lplane + (size_t)buf * bufStride;
        const unsigned short* g = gsrc + laneRowOff + (size_t)t * GBK;
#pragma unroll
        for (int j = 0; j < 8; j++)
            __builtin_amdgcn_global_load_lds((const AS1 void*)(g + (size_t)(j * 16) * K),
                                             (AS3 void*)(d + j * 16 * GBK), 16, 0, 0);
    };

    // prologue: stage tiles 0 and 1; wait tile0 only (tile1 stays in flight)
    STAGE(0, 0);
    STAGE(1, 1);
    asm volatile("s_waitcnt vmcnt(8)\n\ts_barrier" ::: "memory");

    int cur = 0;
    for (int t = 0; t < nt; ++t) {
        // fragment reads from buf[cur] (compiler tracks deps for MFMA)
        shortx8 ah[4], al[4], bh[4], bl[4];
#pragma unroll
        for (int i = 0; i < 4; i++) {
            ah[i] = *reinterpret_cast<const shortx8*>(&As[cur][0][m0 + i * 16 + r16][kswz]);
            al[i] = *reinterpret_cast<const shortx8*>(&As[cur][1][m0 + i * 16 + r16][kswz]);
            bh[i] = *reinterpret_cast<const shortx8*>(&Bs[cur][0][n0 + i * 16 + r16][kswz]);
            bl[i] = *reinterpret_cast<const shortx8*>(&Bs[cur][1][n0 + i * 16 + r16][kswz]);
        }
        // all waves done reading buf[cur] -> safe to overwrite it
        asm volatile("s_waitcnt lgkmcnt(0)\n\ts_barrier" ::: "memory");
        __builtin_amdgcn_sched_barrier(0);
        if (t + 2 < nt) STAGE(t + 2, cur);      // in flight across the MFMA + barrier

        __builtin_amdgcn_s_setprio(1);
#pragma unroll
        for (int i = 0; i < 4; i++)
#pragma unroll
            for (int j = 0; j < 4; j++) {
                acc[i][j] = __builtin_amdgcn_mfma_f32_16x16x32_bf16(ah[i], bh[j], acc[i][j], 0, 0, 0);
                acc[i][j] = __builtin_amdgcn_mfma_f32_16x16x32_bf16(ah[i], bl[j], acc[i][j], 0, 0, 0);
                acc[i][j] = __builtin_amdgcn_mfma_f32_16x16x32_bf16(al[i], bh[j], acc[i][j], 0, 0, 0);
            }
        __builtin_amdgcn_s_setprio(0);

        if (t + 1 < nt) {
            // tile t+1 landed (all 8 of this wave's loads for it retired);
            // t+2's 8 stay outstanding across the barrier (counted, never 0)
            if (t + 2 < nt) asm volatile("s_waitcnt vmcnt(8)\n\ts_barrier" ::: "memory");
            else            asm volatile("s_waitcnt vmcnt(0)\n\ts_barrier" ::: "memory");
            __builtin_amdgcn_sched_barrier(0);
        }
        cur ^= 1;
    }

#pragma unroll
    for (int i = 0; i < 4; i++) {
        int rsub = rowBase + m0 + i * 16 + (lane >> 4) * 4;
#pragma unroll
        for (int j = 0; j < 4; j++) {
            int col = colBase + n0 + j * 16 + r16;
#pragma unroll
            for (int r = 0; r < 4; r++) {
                int row = rsub + r;
                if (row < M) C[(size_t)row * N + col] = f2bf_rne(acc[i][j][r] * dinv[row]);
            }
        }
    }
}

// ---------------------------------------------------------------------------
// Aggregation, layer 1 (F=512 bf16, 64 thr, thread owns 8 channels = 16 B/row):
// out = relu((hs[self] + sum hs[nbr]) * dinv + b), written bf16 hi/lo (NT).
// ---------------------------------------------------------------------------
__global__ __launch_bounds__(64)
void aggregate1_kernel(const unsigned short* __restrict__ hs, const int* __restrict__ offsets,
                       const int* __restrict__ csr_src, const float* __restrict__ dinv,
                       const float* __restrict__ bias,
                       unsigned short* __restrict__ yhi,
                       unsigned short* __restrict__ ylo) {
    __shared__ int idxs[64];
    const int node = blockIdx.x;
    const int c = threadIdx.x * 8;
    const unsigned short* hp = hs + c;

    float acc[8];
    {
        shortx8 r = *reinterpret_cast<const shortx8*>(hp + (size_t)node * HID_DIM);
#pragma unroll
        for (int q = 0; q < 8; q++) acc[q] = bf2f((unsigned short)r[q]);
    }
    int beg = offsets[node], end = offsets[node + 1];
    for (int base = beg; base < end; base += 64) {
        int cnt = min(64, end - base);
        __syncthreads();
        if ((int)threadIdx.x < cnt) idxs[threadIdx.x] = csr_src[base + threadIdx.x];
        __syncthreads();
        int j = 0;
        for (; j + 8 <= cnt; j += 8) {
            shortx8 r0 = *reinterpret_cast<const shortx8*>(hp + (size_t)idxs[j + 0] * HID_DIM);
            shortx8 r1 = *reinterpret_cast<const shortx8*>(hp + (size_t)idxs[j + 1] * HID_DIM);
            shortx8 r2 = *reinterpret_cast<const shortx8*>(hp + (size_t)idxs[j + 2] * HID_DIM);
            shortx8 r3 = *reinterpret_cast<const shortx8*>(hp + (size_t)idxs[j + 3] * HID_DIM);
            shortx8 r4 = *reinterpret_cast<const shortx8*>(hp + (size_t)idxs[j + 4] * HID_DIM);
            shortx8 r5 = *reinterpret_cast<const shortx8*>(hp + (size_t)idxs[j + 5] * HID_DIM);
            shortx8 r6 = *reinterpret_cast<const shortx8*>(hp + (size_t)idxs[j + 6] * HID_DIM);
            shortx8 r7 = *reinterpret_cast<const shortx8*>(hp + (size_t)idxs[j + 7] * HID_DIM);
#pragma unroll
            for (int q = 0; q < 8; q++)
                acc[q] += ((bf2f((unsigned short)r0[q]) + bf2f((unsigned short)r1[q]))
                         + (bf2f((unsigned short)r2[q]) + bf2f((unsigned short)r3[q])))
                        + ((bf2f((unsigned short)r4[q]) + bf2f((unsigned short)r5[q]))
                         + (bf2f((unsigned short)r6[q]) + bf2f((unsigned short)r7[q])));
        }
        for (; j < cnt; j++) {
            shortx8 r = *reinterpret_cast<const shortx8*>(hp + (size_t)idxs[j] * HID_DIM);
#pragma unroll
            for (int q = 0; q < 8; q++) acc[q] += bf2f((unsigned short)r[q]);
        }
    }
    float dv = dinv[node];
    floatx4 b0 = *reinterpret_cast<const floatx4*>(bias + c);
    floatx4 b1 = *reinterpret_cast<const floatx4*>(bias + c + 4);
    shortx8 h8, l8;
#pragma unroll
    for (int q = 0; q < 8; q++) {
        float bq = (q < 4) ? b0[q] : b1[q - 4];
        float o = fmaxf(acc[q] * dv + bq, 0.f);
        unsigned short h = f2bf_rne(o);
        h8[q] = (short)h;
        l8[q] = (short)f2bf_rne(o - bf2f(h));
    }
    __builtin_nontemporal_store(h8, reinterpret_cast<shortx8*>(yhi + (size_t)node * HID_DIM + c));
    __builtin_nontemporal_store(l8, reinterpret_cast<shortx8*>(ylo + (size_t)node * HID_DIM + c));
}

// ---------------------------------------------------------------------------
// Aggregation, layer 2 (F=256 bf16, 64 thr, thread owns 4 channels = 8 B/row):
// fp32 out, no activation, NT store.
// ---------------------------------------------------------------------------
__global__ __launch_bounds__(64)
void aggregate2_kernel(const unsigned short* __restrict__ hs, const int* __restrict__ offsets,
                       const int* __restrict__ csr_src, const float* __restrict__ dinv,
                       const float* __restrict__ bias, float* __restrict__ out) {
    __shared__ int idxs[64];
    const int node = blockIdx.x;
    const int c = threadIdx.x * 4;
    const unsigned short* hp = hs + c;

    float acc[4];
    {
        shortx4 r = *reinterpret_cast<const shortx4*>(hp + (size_t)node * OUT_DIM);
#pragma unroll
        for (int q = 0; q < 4; q++) acc[q] = bf2f((unsigned short)r[q]);
    }
    int beg = offsets[node], end = offsets[node + 1];
    for (int base = beg; base < end; base += 64) {
        int cnt = min(64, end - base);
        __syncthreads();
        if ((int)threadIdx.x < cnt) idxs[threadIdx.x] = csr_src[base + threadIdx.x];
        __syncthreads();
        int j = 0;
        for (; j + 8 <= cnt; j += 8) {
            shortx4 r0 = *reinterpret_cast<const shortx4*>(hp + (size_t)idxs[j + 0] * OUT_DIM);
            shortx4 r1 = *reinterpret_cast<const shortx4*>(hp + (size_t)idxs[j + 1] * OUT_DIM);
            shortx4 r2 = *reinterpret_cast<const shortx4*>(hp + (size_t)idxs[j + 2] * OUT_DIM);
            shortx4 r3 = *reinterpret_cast<const shortx4*>(hp + (size_t)idxs[j + 3] * OUT_DIM);
            shortx4 r4 = *reinterpret_cast<const shortx4*>(hp + (size_t)idxs[j + 4] * OUT_DIM);
            shortx4 r5 = *reinterpret_cast<const shortx4*>(hp + (size_t)idxs[j + 5] * OUT_DIM);
            shortx4 r6 = *reinterpret_cast<const shortx4*>(hp + (size_t)idxs[j + 6] * OUT_DIM);
            shortx4 r7 = *reinterpret_cast<const shortx4*>(hp + (size_t)idxs[j + 7] * OUT_DIM);
#pragma unroll
            for (int q = 0; q < 4; q++)
                acc[q] += ((bf2f((unsigned short)r0[q]) + bf2f((unsigned short)r1[q]))
                         + (bf2f((unsigned short)r2[q]) + bf2f((unsigned short)r3[q])))
                        + ((bf2f((unsigned short)r4[q]) + bf2f((unsigned short)r5[q]))
                         + (bf2f((unsigned short)r6[q]) + bf2f((unsigned short)r7[q])));
        }
        for (; j < cnt; j++) {
            shortx4 r = *reinterpret_cast<const shortx4*>(hp + (size_t)idxs[j] * OUT_DIM);
#pragma unroll
            for (int q = 0; q < 4; q++) acc[q] += bf2f((unsigned short)r[q]);
        }
    }
    float dv = dinv[node];
    floatx4 b = *reinterpret_cast<const floatx4*>(bias + c);
    floatx4 o = { acc[0] * dv + b[0], acc[1] * dv + b[1],
                  acc[2] * dv + b[2], acc[3] * dv + b[3] };
    __builtin_nontemporal_store(o, reinterpret_cast<floatx4*>(out + (size_t)node * OUT_DIM + c));
}

// ---------------------------------------------------------------------------
extern "C" void kernel_launch(void* const* d_in, const int* in_sizes, int n_in,
                              void* d_out, int out_size, void* d_ws, size_t ws_size,
                              hipStream_t stream) {
    const float* x    = (const float*)d_in[0];
    const int*   edge = (const int*)d_in[1];
    const float* W1   = (const float*)d_in[2];
    const float* b1   = (const float*)d_in[3];
    const float* W2   = (const float*)d_in[4];
    const float* b2   = (const float*)d_in[5];
    float* out = (float*)d_out;

    const int* src = edge;
    const int* dst = edge + N_EDGES;

    char*  ws  = (char*)d_ws;
    size_t off = 0;
    auto alloc = [&](size_t bytes) -> void* {
        void* p = ws + off;
        off += (bytes + 255) & ~(size_t)255;
        return p;
    };
    int*   deg      = (int*)alloc((size_t)N_NODES * 4);
    float* dinv     = (float*)alloc((size_t)N_NODES * 4);
    int*   offsets  = (int*)alloc((size_t)(N_NODES + 1) * 4);
    int*   cursor   = (int*)alloc((size_t)N_NODES * 4);
    int*   csr_src  = (int*)alloc((size_t)N_EDGES * 4);
    int*   partials = (int*)alloc((size_t)N_SCAN_BLOCKS * 4);
    int*   bases    = (int*)alloc((size_t)N_SCAN_BLOCKS * 4);
    unsigned short* xhi   = (unsigned short*)alloc((size_t)M_PAD * IN_DIM * 2);
    unsigned short* xlo   = (unsigned short*)alloc((size_t)M_PAD * IN_DIM * 2);
    unsigned short* w1thi = (unsigned short*)alloc((size_t)HID_DIM * IN_DIM * 2);
    unsigned short* w1tlo = (unsigned short*)alloc((size_t)HID_DIM * IN_DIM * 2);
    unsigned short* w2thi = (unsigned short*)alloc((size_t)OUT_DIM * HID_DIM * 2);
    unsigned short* w2tlo = (unsigned short*)alloc((size_t)OUT_DIM * HID_DIM * 2);
    unsigned short* hs = (unsigned short*)alloc((size_t)N_NODES * HID_DIM * 2);  // bf16 pre-agg, reused L2

    unsigned short* y1hi = xhi;   // alias dead x regions
    unsigned short* y1lo = xlo;

    // ---- graph prep ----
    hipMemsetAsync(deg, 0, (size_t)N_NODES * 4, stream);
    count_deg_kernel<<<(N_EDGES + 255) / 256, 256, 0, stream>>>(dst, deg, N_EDGES);
    block_sum_kernel<<<N_SCAN_BLOCKS, SCAN_B, 0, stream>>>(deg, partials, N_NODES);
    scan_partials_kernel<<<1, SCAN_B, 0, stream>>>(partials, bases, N_SCAN_BLOCKS);
    finalize_scan_kernel<<<N_SCAN_BLOCKS, SCAN_B, 0, stream>>>(deg, bases, offsets, cursor,
                                                               dinv, N_NODES);
    fill_csr_kernel<<<(N_EDGES + 255) / 256, 256, 0, stream>>>(src, dst, cursor, csr_src, N_EDGES);

    // ---- precision split ----
    long long n4x = (long long)N_NODES * IN_DIM / 4;
    convert_split_kernel<<<(int)((n4x + 255) / 256), 256, 0, stream>>>(x, xhi, xlo, n4x);
    transpose_split_kernel<<<dim3(HID_DIM / 32, IN_DIM / 32), dim3(32, 32), 0, stream>>>(
        W1, w1thi, w1tlo, IN_DIM, HID_DIM);
    transpose_split_kernel<<<dim3(OUT_DIM / 32, HID_DIM / 32), dim3(32, 32), 0, stream>>>(
        W2, w2thi, w2tlo, HID_DIM, OUT_DIM);

    // ---- layer 1 ----
    gemm_bf16x3_kernel<<<dim3(HID_DIM / 128, M_PAD / 128), 256, 0, stream>>>(
        xhi, xlo, w1thi, w1tlo, dinv, hs, N_NODES, HID_DIM, IN_DIM);
    aggregate1_kernel<<<N_NODES, 64, 0, stream>>>(
        hs, offsets, csr_src, dinv, b1, y1hi, y1lo);

    // ---- layer 2 ----
    gemm_bf16x3_kernel<<<dim3(OUT_DIM / 128, M_PAD / 128), 256, 0, stream>>>(
        y1hi, y1lo, w2thi, w2tlo, dinv, hs, N_NODES, OUT_DIM, HID_DIM);
    aggregate2_kernel<<<N_NODES, 64, 0, stream>>>(
        hs, offsets, csr_src, dinv, b2, out);
}

// Round 5
// 751.177 us; speedup vs baseline: 1.1671x; 1.0552x over previous
//
#include <hip/hip_runtime.h>

#define N_NODES 50000
#define N_EDGES 800000
#define IN_DIM  768
#define HID_DIM 512
#define OUT_DIM 256
#define M_PAD   50048   // 391 * 128

typedef __attribute__((ext_vector_type(8))) short shortx8;        // 8 bf16 = 16 B
typedef __attribute__((ext_vector_type(4))) short shortx4;        // 4 bf16 = 8 B
typedef __attribute__((ext_vector_type(4))) float floatx4;        // MFMA C/D + NT stores

#define AS1 __attribute__((address_space(1)))
#define AS3 __attribute__((address_space(3)))

__device__ __forceinline__ unsigned short f2bf_rne(float f) {
    unsigned int u = __float_as_uint(f);
    unsigned int r = u + 0x7FFFu + ((u >> 16) & 1u);
    return (unsigned short)(r >> 16);
}
__device__ __forceinline__ float bf2f(unsigned short h) {
    return __uint_as_float(((unsigned int)h) << 16);
}

// ---------------------------------------------------------------------------
// Graph prep
// ---------------------------------------------------------------------------
__global__ void count_deg_kernel(const int* __restrict__ dst, int* __restrict__ deg,
                                 int n_edges) {
    int e = blockIdx.x * blockDim.x + threadIdx.x;
    if (e < n_edges) atomicAdd(&deg[dst[e]], 1);
}

#define SCAN_B 256
#define N_SCAN_BLOCKS ((N_NODES + SCAN_B - 1) / SCAN_B)   // 196

__global__ void block_sum_kernel(const int* __restrict__ deg, int* __restrict__ partials,
                                 int n) {
    __shared__ int sm[SCAN_B];
    int i = blockIdx.x * SCAN_B + threadIdx.x;
    sm[threadIdx.x] = (i < n) ? deg[i] : 0;
    __syncthreads();
    for (int off = SCAN_B / 2; off > 0; off >>= 1) {
        if (threadIdx.x < off) sm[threadIdx.x] += sm[threadIdx.x + off];
        __syncthreads();
    }
    if (threadIdx.x == 0) partials[blockIdx.x] = sm[0];
}

__global__ void scan_partials_kernel(const int* __restrict__ partials,
                                     int* __restrict__ bases, int nb) {
    __shared__ int sm[SCAN_B];
    int v = (threadIdx.x < nb) ? partials[threadIdx.x] : 0;
    sm[threadIdx.x] = v;
    __syncthreads();
    for (int off = 1; off < SCAN_B; off <<= 1) {
        int t = (threadIdx.x >= off) ? sm[threadIdx.x - off] : 0;
        __syncthreads();
        sm[threadIdx.x] += t;
        __syncthreads();
    }
    if (threadIdx.x < nb) bases[threadIdx.x] = sm[threadIdx.x] - v;   // exclusive
}

__global__ void finalize_scan_kernel(const int* __restrict__ deg, const int* __restrict__ bases,
                                     int* __restrict__ offsets, int* __restrict__ cursor,
                                     float* __restrict__ dinv, int n) {
    __shared__ int sm[SCAN_B];
    int i = blockIdx.x * SCAN_B + threadIdx.x;
    int v = (i < n) ? deg[i] : 0;
    sm[threadIdx.x] = v;
    __syncthreads();
    for (int off = 1; off < SCAN_B; off <<= 1) {
        int t = (threadIdx.x >= off) ? sm[threadIdx.x - off] : 0;
        __syncthreads();
        sm[threadIdx.x] += t;
        __syncthreads();
    }
    if (i < n) {
        int incl = bases[blockIdx.x] + sm[threadIdx.x];
        int o = incl - v;
        offsets[i] = o;
        cursor[i]  = o;
        dinv[i]    = rsqrtf((float)(v + 1));
        if (i == n - 1) offsets[n] = incl;
    }
}

__global__ void fill_csr_kernel(const int* __restrict__ src, const int* __restrict__ dst,
                                int* __restrict__ cursor, int* __restrict__ csr_src,
                                int n_edges) {
    int e = blockIdx.x * blockDim.x + threadIdx.x;
    if (e < n_edges) {
        int p = atomicAdd(&cursor[dst[e]], 1);
        csr_src[p] = src[e];
    }
}

// ---------------------------------------------------------------------------
// fp32 -> bf16 hi/lo split
// ---------------------------------------------------------------------------
__global__ void convert_split_kernel(const float* __restrict__ x,
                                     unsigned short* __restrict__ xhi,
                                     unsigned short* __restrict__ xlo,
                                     long long n4) {
    long long i = (long long)blockIdx.x * blockDim.x + threadIdx.x;
    if (i >= n4) return;
    float4 v = *reinterpret_cast<const float4*>(x + i * 4);
    ushort4 h, l;
    h.x = f2bf_rne(v.x); l.x = f2bf_rne(v.x - bf2f(h.x));
    h.y = f2bf_rne(v.y); l.y = f2bf_rne(v.y - bf2f(h.y));
    h.z = f2bf_rne(v.z); l.z = f2bf_rne(v.z - bf2f(h.z));
    h.w = f2bf_rne(v.w); l.w = f2bf_rne(v.w - bf2f(h.w));
    *reinterpret_cast<ushort4*>(xhi + i * 4) = h;
    *reinterpret_cast<ushort4*>(xlo + i * 4) = l;
}

// ---------------------------------------------------------------------------
// W [K][N] fp32 -> Wt [N][K] bf16 hi/lo
// ---------------------------------------------------------------------------
__global__ void transpose_split_kernel(const float* __restrict__ W,
                                       unsigned short* __restrict__ Whi,
                                       unsigned short* __restrict__ Wlo,
                                       int K, int N) {
    __shared__ float tile[32][33];
    int n0 = blockIdx.x * 32, k0 = blockIdx.y * 32;
    int tx = threadIdx.x, ty = threadIdx.y;
    tile[ty][tx] = W[(size_t)(k0 + ty) * N + n0 + tx];
    __syncthreads();
    float v = tile[tx][ty];
    unsigned short h = f2bf_rne(v);
    size_t o = (size_t)(n0 + ty) * K + k0 + tx;
    Whi[o] = h;
    Wlo[o] = f2bf_rne(v - bf2f(h));
}

// ---------------------------------------------------------------------------
// bf16x3 split MFMA GEMM (ROUND-2 VERIFIED BEST: 170 us layer-1).
//   C[r][c] = bf16( (sum_k A[r][k]*B[c][k]) * dinv[r] )
//  - T1 XCD-aware bijective block swizzle (FETCH 340->94 MB).
//  - T2 both-sides XOR swizzle (SQ_LDS_BANK_CONFLICT -> 0).
//  - SINGLE-buffer 32 KiB LDS, 2-barrier K-step. Evidence across r1/r3/r4:
//    every pipelining graft (64 KiB dbuf, direct-B, counted-vmcnt) lands at
//    202-255 us -- the 2-phase 128-sq structure's ceiling is here, and
//    occupancy (3-4 blocks/CU at 32 KiB) is what hides the stage latency.
//  - Register diet: B-frags live across K-step, A-frags per-i. VGPR=60.
// ---------------------------------------------------------------------------
#define GBK 32

__global__ __launch_bounds__(256, 4)
void gemm_bf16x3_kernel(const unsigned short* __restrict__ Ahi,
                        const unsigned short* __restrict__ Alo,
                        const unsigned short* __restrict__ Bhi,
                        const unsigned short* __restrict__ Blo,
                        const float* __restrict__ dinv,
                        unsigned short* __restrict__ C,
                        int M, int N, int K) {
    // [hi/lo][row][k] : 2*128*32*2B = 16 KiB each, 32 KiB total
    __shared__ __align__(16) unsigned short As[2][128][GBK];
    __shared__ __align__(16) unsigned short Bs[2][128][GBK];

    const int tid  = threadIdx.x;
    const int lane = tid & 63;
    const int wave = tid >> 6;

    // --- XCD-aware bijective swizzle (m204 formula) ---
    const int gx   = gridDim.x;
    const int nwg  = gx * gridDim.y;
    const int blin = blockIdx.y * gx + blockIdx.x;      // hw linear id, x fastest
    const int qq   = nwg >> 3, rr = nwg & 7;
    const int xcd  = blin & 7, idx = blin >> 3;
    const int tt   = (xcd < rr ? xcd * (qq + 1) : rr * (qq + 1) + (xcd - rr) * qq) + idx;
    const int rowBase = (tt / gx) * 128;
    const int colBase = (tt % gx) * 128;

    const unsigned short* gsrc =
        (wave == 0) ? Ahi : (wave == 1) ? Alo : (wave == 2) ? Bhi : Blo;
    unsigned short* lbase =
        (wave == 0) ? &As[0][0][0] : (wave == 1) ? &As[1][0][0]
      : (wave == 2) ? &Bs[0][0][0] : &Bs[1][0][0];
    const int rbase = (wave < 2) ? rowBase : colBase;
    // pre-swizzled global col-group so LDS[r][s] holds col-group s ^ ((r>>1)&3)
    const int cg = ((lane & 3) ^ ((lane >> 3) & 3)) * 8;
    const size_t laneRowOff = (size_t)(rbase + (lane >> 2)) * K + cg;

    const int m0  = (wave & 1) * 64;
    const int n0  = (wave >> 1) * 64;
    const int r16 = lane & 15;
    // matching read-side XOR: logical col-group (lane>>4), physical slot XORed
    const int kswz = ((lane >> 4) ^ ((r16 >> 1) & 3)) * 8;

    floatx4 acc[4][4] = {};

    for (int k0 = 0; k0 < K; k0 += GBK) {
#pragma unroll
        for (int j = 0; j < 8; j++) {
            const unsigned short* g = gsrc + laneRowOff + (size_t)(j * 16) * K + k0;
            __builtin_amdgcn_global_load_lds((const AS1 void*)g,
                                             (AS3 void*)(lbase + j * 16 * GBK),
                                             16, 0, 0);
        }
        __syncthreads();

        // B fragments live across the whole K-step (32 VGPR)
        shortx8 bh[4], bv[4];
#pragma unroll
        for (int j = 0; j < 4; j++) {
            bh[j] = *reinterpret_cast<const shortx8*>(&Bs[0][n0 + j * 16 + r16][kswz]);
            bv[j] = *reinterpret_cast<const shortx8*>(&Bs[1][n0 + j * 16 + r16][kswz]);
        }
        // A fragments loaded per i (8 VGPR live) -> peak live ~40 regs
#pragma unroll
        for (int i = 0; i < 4; i++) {
            shortx8 ah = *reinterpret_cast<const shortx8*>(&As[0][m0 + i * 16 + r16][kswz]);
            shortx8 al = *reinterpret_cast<const shortx8*>(&As[1][m0 + i * 16 + r16][kswz]);
#pragma unroll
            for (int j = 0; j < 4; j++) {
                acc[i][j] = __builtin_amdgcn_mfma_f32_16x16x32_bf16(ah, bh[j], acc[i][j], 0, 0, 0);
                acc[i][j] = __builtin_amdgcn_mfma_f32_16x16x32_bf16(ah, bv[j], acc[i][j], 0, 0, 0);
                acc[i][j] = __builtin_amdgcn_mfma_f32_16x16x32_bf16(al, bh[j], acc[i][j], 0, 0, 0);
            }
        }
        __syncthreads();
    }

#pragma unroll
    for (int i = 0; i < 4; i++) {
        int rsub = rowBase + m0 + i * 16 + (lane >> 4) * 4;
#pragma unroll
        for (int j = 0; j < 4; j++) {
            int col = colBase + n0 + j * 16 + r16;
#pragma unroll
            for (int r = 0; r < 4; r++) {
                int row = rsub + r;
                if (row < M) C[(size_t)row * N + col] = f2bf_rne(acc[i][j][r] * dinv[row]);
            }
        }
    }
}

// ---------------------------------------------------------------------------
// Aggregation, layer 1 -- WAVE-PER-NODE, barrier-free (round-5 redesign).
// 256-thr block = 4 waves = 4 nodes. Neighbor indices: coalesced one-per-lane
// load + __shfl broadcast (unrolled const lanes -> v_readlane + SGPR-base
// row loads). No LDS, no __syncthreads. 16 gather rows in flight (two 8-trees
// summed in the SAME order as before -> bit-identical numerics).
// out = relu((hs[self] + sum hs[nbr]) * dinv + b), written bf16 hi/lo (NT).
// ---------------------------------------------------------------------------
__global__ __launch_bounds__(256)
void aggregate1_kernel(const unsigned short* __restrict__ hs, const int* __restrict__ offsets,
                       const int* __restrict__ csr_src, const float* __restrict__ dinv,
                       const float* __restrict__ bias,
                       unsigned short* __restrict__ yhi,
                       unsigned short* __restrict__ ylo) {
    const int wave = threadIdx.x >> 6;
    const int lane = threadIdx.x & 63;
    const int node = blockIdx.x * 4 + wave;
    const int c = lane * 8;
    const unsigned short* hp = hs + c;

    // hoist scalar/row loads ahead of the gather
    const int beg = offsets[node], end = offsets[node + 1];
    const float dv = dinv[node];
    floatx4 b0 = *reinterpret_cast<const floatx4*>(bias + c);
    floatx4 b1 = *reinterpret_cast<const floatx4*>(bias + c + 4);

    float acc[8];
    {
        shortx8 r = *reinterpret_cast<const shortx8*>(hp + (size_t)node * HID_DIM);
#pragma unroll
        for (int q = 0; q < 8; q++) acc[q] = bf2f((unsigned short)r[q]);
    }

#define A1_SUM8(r0,r1,r2,r3,r4,r5,r6,r7)                                        \
    _Pragma("unroll")                                                            \
    for (int q = 0; q < 8; q++)                                                  \
        acc[q] += ((bf2f((unsigned short)r0[q]) + bf2f((unsigned short)r1[q]))   \
                 + (bf2f((unsigned short)r2[q]) + bf2f((unsigned short)r3[q])))  \
                + ((bf2f((unsigned short)r4[q]) + bf2f((unsigned short)r5[q]))   \
                 + (bf2f((unsigned short)r6[q]) + bf2f((unsigned short)r7[q])));

    for (int base = beg; base < end; base += 64) {
        int cnt = min(64, end - base);
        int myidx = (base + lane < end) ? csr_src[base + lane] : 0;   // coalesced
        int j = 0;
        for (; j + 16 <= cnt; j += 16) {
            // 16 rows in flight; sums stay two sequential 8-trees (bit-identical)
            shortx8 r0 = *reinterpret_cast<const shortx8*>(hp + (size_t)__shfl(myidx, j + 0) * HID_DIM);
            shortx8 r1 = *reinterpret_cast<const shortx8*>(hp + (size_t)__shfl(myidx, j + 1) * HID_DIM);
            shortx8 r2 = *reinterpret_cast<const shortx8*>(hp + (size_t)__shfl(myidx, j + 2) * HID_DIM);
            shortx8 r3 = *reinterpret_cast<const shortx8*>(hp + (size_t)__shfl(myidx, j + 3) * HID_DIM);
            shortx8 r4 = *reinterpret_cast<const shortx8*>(hp + (size_t)__shfl(myidx, j + 4) * HID_DIM);
            shortx8 r5 = *reinterpret_cast<const shortx8*>(hp + (size_t)__shfl(myidx, j + 5) * HID_DIM);
            shortx8 r6 = *reinterpret_cast<const shortx8*>(hp + (size_t)__shfl(myidx, j + 6) * HID_DIM);
            shortx8 r7 = *reinterpret_cast<const shortx8*>(hp + (size_t)__shfl(myidx, j + 7) * HID_DIM);
            shortx8 r8 = *reinterpret_cast<const shortx8*>(hp + (size_t)__shfl(myidx, j + 8) * HID_DIM);
            shortx8 r9 = *reinterpret_cast<const shortx8*>(hp + (size_t)__shfl(myidx, j + 9) * HID_DIM);
            shortx8 ra = *reinterpret_cast<const shortx8*>(hp + (size_t)__shfl(myidx, j + 10) * HID_DIM);
            shortx8 rb = *reinterpret_cast<const shortx8*>(hp + (size_t)__shfl(myidx, j + 11) * HID_DIM);
            shortx8 rc = *reinterpret_cast<const shortx8*>(hp + (size_t)__shfl(myidx, j + 12) * HID_DIM);
            shortx8 rd = *reinterpret_cast<const shortx8*>(hp + (size_t)__shfl(myidx, j + 13) * HID_DIM);
            shortx8 re = *reinterpret_cast<const shortx8*>(hp + (size_t)__shfl(myidx, j + 14) * HID_DIM);
            shortx8 rf = *reinterpret_cast<const shortx8*>(hp + (size_t)__shfl(myidx, j + 15) * HID_DIM);
            A1_SUM8(r0, r1, r2, r3, r4, r5, r6, r7)
            A1_SUM8(r8, r9, ra, rb, rc, rd, re, rf)
        }
        for (; j + 8 <= cnt; j += 8) {
            shortx8 r0 = *reinterpret_cast<const shortx8*>(hp + (size_t)__shfl(myidx, j + 0) * HID_DIM);
            shortx8 r1 = *reinterpret_cast<const shortx8*>(hp + (size_t)__shfl(myidx, j + 1) * HID_DIM);
            shortx8 r2 = *reinterpret_cast<const shortx8*>(hp + (size_t)__shfl(myidx, j + 2) * HID_DIM);
            shortx8 r3 = *reinterpret_cast<const shortx8*>(hp + (size_t)__shfl(myidx, j + 3) * HID_DIM);
            shortx8 r4 = *reinterpret_cast<const shortx8*>(hp + (size_t)__shfl(myidx, j + 4) * HID_DIM);
            shortx8 r5 = *reinterpret_cast<const shortx8*>(hp + (size_t)__shfl(myidx, j + 5) * HID_DIM);
            shortx8 r6 = *reinterpret_cast<const shortx8*>(hp + (size_t)__shfl(myidx, j + 6) * HID_DIM);
            shortx8 r7 = *reinterpret_cast<const shortx8*>(hp + (size_t)__shfl(myidx, j + 7) * HID_DIM);
            A1_SUM8(r0, r1, r2, r3, r4, r5, r6, r7)
        }
        for (; j < cnt; j++) {
            shortx8 r = *reinterpret_cast<const shortx8*>(hp + (size_t)__shfl(myidx, j) * HID_DIM);
#pragma unroll
            for (int q = 0; q < 8; q++) acc[q] += bf2f((unsigned short)r[q]);
        }
    }
#undef A1_SUM8

    shortx8 h8, l8;
#pragma unroll
    for (int q = 0; q < 8; q++) {
        float bq = (q < 4) ? b0[q] : b1[q - 4];
        float o = fmaxf(acc[q] * dv + bq, 0.f);
        unsigned short h = f2bf_rne(o);
        h8[q] = (short)h;
        l8[q] = (short)f2bf_rne(o - bf2f(h));
    }
    __builtin_nontemporal_store(h8, reinterpret_cast<shortx8*>(yhi + (size_t)node * HID_DIM + c));
    __builtin_nontemporal_store(l8, reinterpret_cast<shortx8*>(ylo + (size_t)node * HID_DIM + c));
}

// ---------------------------------------------------------------------------
// Aggregation, layer 2 -- same wave-per-node redesign (F=256, 8 B/lane/row).
// fp32 out, no activation, NT store.
// ---------------------------------------------------------------------------
__global__ __launch_bounds__(256)
void aggregate2_kernel(const unsigned short* __restrict__ hs, const int* __restrict__ offsets,
                       const int* __restrict__ csr_src, const float* __restrict__ dinv,
                       const float* __restrict__ bias, float* __restrict__ out) {
    const int wave = threadIdx.x >> 6;
    const int lane = threadIdx.x & 63;
    const int node = blockIdx.x * 4 + wave;
    const int c = lane * 4;
    const unsigned short* hp = hs + c;

    const int beg = offsets[node], end = offsets[node + 1];
    const float dv = dinv[node];
    floatx4 b = *reinterpret_cast<const floatx4*>(bias + c);

    float acc[4];
    {
        shortx4 r = *reinterpret_cast<const shortx4*>(hp + (size_t)node * OUT_DIM);
#pragma unroll
        for (int q = 0; q < 4; q++) acc[q] = bf2f((unsigned short)r[q]);
    }

#define A2_SUM8(r0,r1,r2,r3,r4,r5,r6,r7)                                        \
    _Pragma("unroll")                                                            \
    for (int q = 0; q < 4; q++)                                                  \
        acc[q] += ((bf2f((unsigned short)r0[q]) + bf2f((unsigned short)r1[q]))   \
                 + (bf2f((unsigned short)r2[q]) + bf2f((unsigned short)r3[q])))  \
                + ((bf2f((unsigned short)r4[q]) + bf2f((unsigned short)r5[q]))   \
                 + (bf2f((unsigned short)r6[q]) + bf2f((unsigned short)r7[q])));

    for (int base = beg; base < end; base += 64) {
        int cnt = min(64, end - base);
        int myidx = (base + lane < end) ? csr_src[base + lane] : 0;   // coalesced
        int j = 0;
        for (; j + 16 <= cnt; j += 16) {
            shortx4 r0 = *reinterpret_cast<const shortx4*>(hp + (size_t)__shfl(myidx, j + 0) * OUT_DIM);
            shortx4 r1 = *reinterpret_cast<const shortx4*>(hp + (size_t)__shfl(myidx, j + 1) * OUT_DIM);
            shortx4 r2 = *reinterpret_cast<const shortx4*>(hp + (size_t)__shfl(myidx, j + 2) * OUT_DIM);
            shortx4 r3 = *reinterpret_cast<const shortx4*>(hp + (size_t)__shfl(myidx, j + 3) * OUT_DIM);
            shortx4 r4 = *reinterpret_cast<const shortx4*>(hp + (size_t)__shfl(myidx, j + 4) * OUT_DIM);
            shortx4 r5 = *reinterpret_cast<const shortx4*>(hp + (size_t)__shfl(myidx, j + 5) * OUT_DIM);
            shortx4 r6 = *reinterpret_cast<const shortx4*>(hp + (size_t)__shfl(myidx, j + 6) * OUT_DIM);
            shortx4 r7 = *reinterpret_cast<const shortx4*>(hp + (size_t)__shfl(myidx, j + 7) * OUT_DIM);
            shortx4 r8 = *reinterpret_cast<const shortx4*>(hp + (size_t)__shfl(myidx, j + 8) * OUT_DIM);
            shortx4 r9 = *reinterpret_cast<const shortx4*>(hp + (size_t)__shfl(myidx, j + 9) * OUT_DIM);
            shortx4 ra = *reinterpret_cast<const shortx4*>(hp + (size_t)__shfl(myidx, j + 10) * OUT_DIM);
            shortx4 rb = *reinterpret_cast<const shortx4*>(hp + (size_t)__shfl(myidx, j + 11) * OUT_DIM);
            shortx4 rc = *reinterpret_cast<const shortx4*>(hp + (size_t)__shfl(myidx, j + 12) * OUT_DIM);
            shortx4 rd = *reinterpret_cast<const shortx4*>(hp + (size_t)__shfl(myidx, j + 13) * OUT_DIM);
            shortx4 re = *reinterpret_cast<const shortx4*>(hp + (size_t)__shfl(myidx, j + 14) * OUT_DIM);
            shortx4 rf = *reinterpret_cast<const shortx4*>(hp + (size_t)__shfl(myidx, j + 15) * OUT_DIM);
            A2_SUM8(r0, r1, r2, r3, r4, r5, r6, r7)
            A2_SUM8(r8, r9, ra, rb, rc, rd, re, rf)
        }
        for (; j + 8 <= cnt; j += 8) {
            shortx4 r0 = *reinterpret_cast<const shortx4*>(hp + (size_t)__shfl(myidx, j + 0) * OUT_DIM);
            shortx4 r1 = *reinterpret_cast<const shortx4*>(hp + (size_t)__shfl(myidx, j + 1) * OUT_DIM);
            shortx4 r2 = *reinterpret_cast<const shortx4*>(hp + (size_t)__shfl(myidx, j + 2) * OUT_DIM);
            shortx4 r3 = *reinterpret_cast<const shortx4*>(hp + (size_t)__shfl(myidx, j + 3) * OUT_DIM);
            shortx4 r4 = *reinterpret_cast<const shortx4*>(hp + (size_t)__shfl(myidx, j + 4) * OUT_DIM);
            shortx4 r5 = *reinterpret_cast<const shortx4*>(hp + (size_t)__shfl(myidx, j + 5) * OUT_DIM);
            shortx4 r6 = *reinterpret_cast<const shortx4*>(hp + (size_t)__shfl(myidx, j + 6) * OUT_DIM);
            shortx4 r7 = *reinterpret_cast<const shortx4*>(hp + (size_t)__shfl(myidx, j + 7) * OUT_DIM);
            A2_SUM8(r0, r1, r2, r3, r4, r5, r6, r7)
        }
        for (; j < cnt; j++) {
            shortx4 r = *reinterpret_cast<const shortx4*>(hp + (size_t)__shfl(myidx, j) * OUT_DIM);
#pragma unroll
            for (int q = 0; q < 4; q++) acc[q] += bf2f((unsigned short)r[q]);
        }
    }
#undef A2_SUM8

    floatx4 o = { acc[0] * dv + b[0], acc[1] * dv + b[1],
                  acc[2] * dv + b[2], acc[3] * dv + b[3] };
    __builtin_nontemporal_store(o, reinterpret_cast<floatx4*>(out + (size_t)node * OUT_DIM + c));
}

// ---------------------------------------------------------------------------
extern "C" void kernel_launch(void* const* d_in, const int* in_sizes, int n_in,
                              void* d_out, int out_size, void* d_ws, size_t ws_size,
                              hipStream_t stream) {
    const float* x    = (const float*)d_in[0];
    const int*   edge = (const int*)d_in[1];
    const float* W1   = (const float*)d_in[2];
    const float* b1   = (const float*)d_in[3];
    const float* W2   = (const float*)d_in[4];
    const float* b2   = (const float*)d_in[5];
    float* out = (float*)d_out;

    const int* src = edge;
    const int* dst = edge + N_EDGES;

    char*  ws  = (char*)d_ws;
    size_t off = 0;
    auto alloc = [&](size_t bytes) -> void* {
        void* p = ws + off;
        off += (bytes + 255) & ~(size_t)255;
        return p;
    };
    int*   deg      = (int*)alloc((size_t)N_NODES * 4);
    float* dinv     = (float*)alloc((size_t)N_NODES * 4);
    int*   offsets  = (int*)alloc((size_t)(N_NODES + 1) * 4);
    int*   cursor   = (int*)alloc((size_t)N_NODES * 4);
    int*   csr_src  = (int*)alloc((size_t)N_EDGES * 4);
    int*   partials = (int*)alloc((size_t)N_SCAN_BLOCKS * 4);
    int*   bases    = (int*)alloc((size_t)N_SCAN_BLOCKS * 4);
    unsigned short* xhi   = (unsigned short*)alloc((size_t)M_PAD * IN_DIM * 2);
    unsigned short* xlo   = (unsigned short*)alloc((size_t)M_PAD * IN_DIM * 2);
    unsigned short* w1thi = (unsigned short*)alloc((size_t)HID_DIM * IN_DIM * 2);
    unsigned short* w1tlo = (unsigned short*)alloc((size_t)HID_DIM * IN_DIM * 2);
    unsigned short* w2thi = (unsigned short*)alloc((size_t)OUT_DIM * HID_DIM * 2);
    unsigned short* w2tlo = (unsigned short*)alloc((size_t)OUT_DIM * HID_DIM * 2);
    unsigned short* hs = (unsigned short*)alloc((size_t)N_NODES * HID_DIM * 2);  // bf16 pre-agg, reused L2

    unsigned short* y1hi = xhi;   // alias dead x regions
    unsigned short* y1lo = xlo;

    // ---- graph prep ----
    hipMemsetAsync(deg, 0, (size_t)N_NODES * 4, stream);
    count_deg_kernel<<<(N_EDGES + 255) / 256, 256, 0, stream>>>(dst, deg, N_EDGES);
    block_sum_kernel<<<N_SCAN_BLOCKS, SCAN_B, 0, stream>>>(deg, partials, N_NODES);
    scan_partials_kernel<<<1, SCAN_B, 0, stream>>>(partials, bases, N_SCAN_BLOCKS);
    finalize_scan_kernel<<<N_SCAN_BLOCKS, SCAN_B, 0, stream>>>(deg, bases, offsets, cursor,
                                                               dinv, N_NODES);
    fill_csr_kernel<<<(N_EDGES + 255) / 256, 256, 0, stream>>>(src, dst, cursor, csr_src, N_EDGES);

    // ---- precision split ----
    long long n4x = (long long)N_NODES * IN_DIM / 4;
    convert_split_kernel<<<(int)((n4x + 255) / 256), 256, 0, stream>>>(x, xhi, xlo, n4x);
    transpose_split_kernel<<<dim3(HID_DIM / 32, IN_DIM / 32), dim3(32, 32), 0, stream>>>(
        W1, w1thi, w1tlo, IN_DIM, HID_DIM);
    transpose_split_kernel<<<dim3(OUT_DIM / 32, HID_DIM / 32), dim3(32, 32), 0, stream>>>(
        W2, w2thi, w2tlo, HID_DIM, OUT_DIM);

    // ---- layer 1 ----
    gemm_bf16x3_kernel<<<dim3(HID_DIM / 128, M_PAD / 128), 256, 0, stream>>>(
        xhi, xlo, w1thi, w1tlo, dinv, hs, N_NODES, HID_DIM, IN_DIM);
    aggregate1_kernel<<<N_NODES / 4, 256, 0, stream>>>(
        hs, offsets, csr_src, dinv, b1, y1hi, y1lo);

    // ---- layer 2 ----
    gemm_bf16x3_kernel<<<dim3(OUT_DIM / 128, M_PAD / 128), 256, 0, stream>>>(
        y1hi, y1lo, w2thi, w2tlo, dinv, hs, N_NODES, OUT_DIM, HID_DIM);
    aggregate2_kernel<<<N_NODES / 4, 256, 0, stream>>>(
        hs, offsets, csr_src, dinv, b2, out);
}